// Round 15
// baseline (824.367 us; speedup 1.0000x reference)
//
#include <hip/hip_runtime.h>
#include <cmath>

#define KNB 32
#define HDIM 64

// ws layout (floats):
#define W1T_OFF 0                   // [64][6]  W1T[j][f] = W1[f][j]
#define W2BT_OFF (384 + 4096)       // [64][64] W2bT[j][i] = W2[64+i][j]
#define COV_OFF 8704                // [N][6]   f32 cov (c00,c10,c20,c11,c21,c22)

// ---------------- prep: transpose weights into ws ----------------
__global__ void prep_kernel(const float* __restrict__ W1, const float* __restrict__ W2,
                            float* __restrict__ ws) {
    int t = blockIdx.x * blockDim.x + threadIdx.x;
    if (t < 384) {
        int j = t / 6, f = t - j * 6;
        ws[W1T_OFF + t] = W1[f * HDIM + j];
    }
    if (t < 4096) {
        int j = t >> 6, i = t & 63;
        ws[W2BT_OFF + t] = W2[(HDIM + i) * HDIM + j];
    }
}

// numpy SIMD exp_FLOAT emulation (Cephes poly, FMA, rint quadrant, exact scale).
__device__ inline float numpy_expf(float x) {
#pragma clang fp contract(off)
    const float LOG2E = 1.44269504088896341f;
    const float C1 = 0.693359375f;              // ln2 hi (Cody-Waite)
    const float C2 = -2.12194440e-4f;           // ln2 lo
    float q = rintf(x * LOG2E);
    float r = fmaf(q, -C1, x);
    r = fmaf(q, -C2, r);
    float p = 1.9875691500e-4f;
    p = fmaf(p, r, 1.3981999507e-3f);
    p = fmaf(p, r, 8.3334519073e-3f);
    p = fmaf(p, r, 4.1665795894e-2f);
    p = fmaf(p, r, 1.6666665459e-1f);
    p = fmaf(p, r, 5.0000001201e-1f);
    float r2 = r * r;
    p = fmaf(r2, p, r);
    p = p + 1.0f;
    return ldexpf(p, (int)q);
}

// ---------------- MLP + weights + cov ----------------
// R15: R13 structure (outer-product 4x16 tiles), but phase-3 W2 reads go
// through the VECTOR memory path instead of s_load: pointer offset by
// lz = idx>>31 (runtime-loaded, always 0, unprovable) makes the address
// formally lane-varying -> global_load_dwordx4 with deep vmcnt pipelining
// into VGPRs; W2 (16 KB) is L1-resident (32 KB/CU). This attacks the
// shallow scalar-load queue (SGPR-capped ~3 tiles in flight, K$ thrash)
// identified as the R12/R13 ~45%-issue invariant. DS staging (R14) is
// reverted: uniform ds_read_b128 cost 12 cyc/inst on the DS pipe and
// REGRESSED. All FMA chain orders identical to R13 -> bit-exact.
__global__ __launch_bounds__(256)
void gnn_kernel(const float* __restrict__ old_w, const float* __restrict__ pos,
                const float* __restrict__ nrm, const int* __restrict__ dense,
                const float* __restrict__ sd_p, const float* __restrict__ b1,
                const float* __restrict__ b2, const float* __restrict__ W3,
                const float* __restrict__ b3, const float* __restrict__ W2orig,
                const float* __restrict__ wsW,
                float* __restrict__ out_w, float* __restrict__ cov_out, int N)
{
#pragma clang fp contract(off)
    const int wave = threadIdx.x >> 6;
    const int lane = threadIdx.x & 63;
    const int half = lane >> 5;
    const int k = lane & 31;
    const int pt_slot = wave * 2 + half;
    const int n = blockIdx.x * 8 + pt_slot;
    const bool valid = (n < N);
    const int nn = valid ? n : 0;

    __shared__ float aggterm_s[8][HDIM];
    __shared__ float edat[8][KNB][4];   // rx,ry,rz,w per edge

    // ---- phase 1: per-edge features (numpy evaluation order, no contraction) ----
    int idx = dense[nn * KNB + k];
    // lz == 0 always (dense holds indices in [0,N)), but the compiler cannot
    // prove it: keeps phase-3 W2 addresses lane-varying -> vector loads.
    const int lz = idx >> 31;
    float px = pos[nn * 3 + 0], py = pos[nn * 3 + 1], pz = pos[nn * 3 + 2];
    float rx = pos[idx * 3 + 0] - px;
    float ry = pos[idx * 3 + 1] - py;
    float rz = pos[idx * 3 + 2] - pz;
    float dist = sqrtf((rx * rx + ry * ry) + rz * rz);
    float nx = nrm[nn * 3 + 0], ny = nrm[nn * 3 + 1], nz = nrm[nn * 3 + 2];
    float ndot = fabsf((nx * rx + ny * ry) + nz * rz) / (dist + 1e-8f);
    float sd = sd_p[0];
    float f0 = rx / sd, f1 = ry / sd, f2 = rz / sd, f3 = dist / sd;
    float f4 = ndot, f5 = old_w[nn * KNB + k];

    // ---- phase 2: h[j] = relu(feat @ W1 + b1), K=6 FMA chain, bias after ----
    float h[HDIM];
#pragma unroll
    for (int j = 0; j < HDIM; ++j) {
        const float* w1r = wsW + W1T_OFF + j * 6;   // uniform -> s_load
        float a = f0 * w1r[0];
        a = fmaf(f1, w1r[1], a);
        a = fmaf(f2, w1r[2], a);
        a = fmaf(f3, w1r[3], a);
        a = fmaf(f4, w1r[4], a);
        a = fmaf(f5, w1r[5], a);
        a = a + b1[j];
        h[j] = fmaxf(a, 0.0f);
    }

    // ---- fused agg-reduce + cooperative aggterm (lane k -> j=k, k+32) ----
    {
        float t0 = 0.0f, t1 = 0.0f;
        const float4* r0 = (const float4*)(wsW + W2BT_OFF + k * HDIM);
        const float4* r1 = (const float4*)(wsW + W2BT_OFF + (k + 32) * HDIM);
#pragma unroll
        for (int i4 = 0; i4 < HDIM / 4; ++i4) {
            float4 a0 = r0[i4], a1 = r1[i4];
#pragma unroll
            for (int t = 0; t < 4; ++t) {
                float m = h[4 * i4 + t];
                m = fmaxf(m, __shfl_xor(m, 1, 64));
                m = fmaxf(m, __shfl_xor(m, 2, 64));
                m = fmaxf(m, __shfl_xor(m, 4, 64));
                m = fmaxf(m, __shfl_xor(m, 8, 64));
                m = fmaxf(m, __shfl_xor(m, 16, 64));
                float w0 = (t == 0) ? a0.x : (t == 1) ? a0.y : (t == 2) ? a0.z : a0.w;
                float w1v = (t == 0) ? a1.x : (t == 1) ? a1.y : (t == 2) ? a1.z : a1.w;
                t0 = fmaf(m, w0, t0);
                t1 = fmaf(m, w1v, t1);
            }
        }
        aggterm_s[pt_slot][k] = t0;
        aggterm_s[pt_slot][k + 32] = t1;
    }
    // written and read by the same 32-lane half; compiler's lgkmcnt orders it.

    // ---- phase 3: outer-product tiles, W2 via vector L1 path; pv j-ascending ----
    float pv = 0.0f;
    const float* atrow = aggterm_s[pt_slot];
    const float* w2v = W2orig + lz;     // lane-varying in form, 0-offset in fact
    for (int jb = 0; jb < 4; ++jb) {
        float acc16[16];
#pragma unroll
        for (int i = 0; i < HDIM; ++i) {
            const float4* w2r = (const float4*)(w2v + i * HDIM + jb * 16);  // global_load_dwordx4 x4 (L1 broadcast)
            float4 q0 = w2r[0], q1 = w2r[1], q2 = w2r[2], q3 = w2r[3];
            float qa[16] = {q0.x, q0.y, q0.z, q0.w, q1.x, q1.y, q1.z, q1.w,
                            q2.x, q2.y, q2.z, q2.w, q3.x, q3.y, q3.z, q3.w};
            float hi = h[i];
            if (i == 0) {
#pragma unroll
                for (int jj = 0; jj < 16; ++jj) acc16[jj] = hi * qa[jj];
            } else {
#pragma unroll
                for (int jj = 0; jj < 16; ++jj) acc16[jj] = fmaf(hi, qa[jj], acc16[jj]);
            }
        }
#pragma unroll
        for (int jj = 0; jj < 16; ++jj) {
            int j = jb * 16 + jj;
            float a = (acc16[jj] + atrow[j]) + b2[j];
            float h2 = fmaxf(a, 0.0f);
            pv = fmaf(h2, W3[j], pv);
        }
    }
    float t = -(pv + b3[0]);
    float wk = 1.0f / (1.0f + numpy_expf(t));
    if (valid) out_w[nn * KNB + k] = wk;

    // ---- cov in numpy-einsum order, lower-triangle product order ----
    edat[pt_slot][k][0] = rx;
    edat[pt_slot][k][1] = ry;
    edat[pt_slot][k][2] = rz;
    edat[pt_slot][k][3] = wk;
    __syncthreads();
    if (valid && k < 6) {
        const int EI[6] = {0, 1, 2, 1, 2, 2};
        const int EJ[6] = {0, 0, 0, 1, 1, 2};
        int ei = EI[k], ej = EJ[k];
        float acc = 0.0f;
        for (int kk = 0; kk < KNB; ++kk) {
            float w = edat[pt_slot][kk][3];
            acc = acc + (w * edat[pt_slot][kk][ei]) * edat[pt_slot][kk][ej];
        }
        cov_out[n * 6 + k] = acc;
    }
}

// ================= LAPACK-faithful SINGLE-PRECISION 3x3 eigensolver =================
// Model: LAPACK Fortran (ssteqr/slaev2/slartg/slarfg) = baseline x86-64, NO FMA
// (contract off, mul+add). BLAS kernels called by ssytd2/slarf (ssymv, sdot,
// saxpy, ssyr2, sgemv, sger) = OpenBLAS arch-dispatched C kernels compiled with
// -mfma -ffp-contract=fast: every "acc += a*b" is an FMA. slartg >= 3.10.

__device__ inline float slapy2f(float x, float y) {
#pragma clang fp contract(off)
    float ax = fabsf(x), ay = fabsf(y);
    float w = fmaxf(ax, ay), z = fminf(ax, ay);
    if (z == 0.0f) return w;
    float q = z / w;
    return w * sqrtf(1.0f + q * q);
}

// LAPACK >= 3.10 slartg (f32, moderate-magnitude path)
__device__ inline void slartg_f(float f, float g, float& c, float& s, float& r) {
#pragma clang fp contract(off)
    if (g == 0.0f) { c = 1.0f; s = 0.0f; r = f; }
    else if (f == 0.0f) { c = 0.0f; s = copysignf(1.0f, g); r = fabsf(g); }
    else {
        float d = sqrtf(f * f + g * g);
        c = fabsf(f) / d;
        r = copysignf(d, f);
        s = g / r;
    }
}

__device__ void slaev2_f(float a, float b, float c, float& rt1, float& rt2,
                         float& cs1, float& sn1) {
#pragma clang fp contract(off)
    float sm = a + c, df = a - c, adf = fabsf(df), tb = b + b, ab = fabsf(tb);
    float acmx, acmn;
    if (fabsf(a) > fabsf(c)) { acmx = a; acmn = c; } else { acmx = c; acmn = a; }
    float rt;
    if (adf > ab)      { float q = ab / adf; rt = adf * sqrtf(1.0f + q * q); }
    else if (adf < ab) { float q = adf / ab; rt = ab * sqrtf(1.0f + q * q); }
    else               { rt = ab * sqrtf(2.0f); }
    int sgn1;
    if (sm < 0.0f)      { rt1 = 0.5f * (sm - rt); sgn1 = -1; rt2 = (acmx / rt1) * acmn - (b / rt1) * b; }
    else if (sm > 0.0f) { rt1 = 0.5f * (sm + rt); sgn1 = 1;  rt2 = (acmx / rt1) * acmn - (b / rt1) * b; }
    else                { rt1 = 0.5f * rt; rt2 = -0.5f * rt; sgn1 = 1; }
    float cs; int sgn2;
    if (df >= 0.0f) { cs = df + rt; sgn2 = 1; } else { cs = df - rt; sgn2 = -1; }
    float acs = fabsf(cs);
    if (acs > ab) { float ct = -tb / cs; sn1 = 1.0f / sqrtf(1.0f + ct * ct); cs1 = ct * sn1; }
    else {
        if (ab == 0.0f) { cs1 = 1.0f; sn1 = 0.0f; }
        else { float tn = -cs / tb; cs1 = 1.0f / sqrtf(1.0f + tn * tn); sn1 = tn * cs1; }
    }
    if (sgn1 == sgn2) { float tn = cs1; cs1 = -sn1; sn1 = tn; }
}

// apply right rotation to Z columns (ca, ca+1) per SLASR 'R','V' (identity-skip)
__device__ inline void rot_pair(float Z[3][3], int ca, float cc, float ss) {
#pragma clang fp contract(off)
    if (cc == 1.0f && ss == 0.0f) return;
    if (ca == 0) {
#pragma unroll
        for (int i = 0; i < 3; ++i) { float t = Z[i][1]; Z[i][1] = cc * t - ss * Z[i][0]; Z[i][0] = ss * t + cc * Z[i][0]; }
    } else {
#pragma unroll
        for (int i = 0; i < 3; ++i) { float t = Z[i][2]; Z[i][2] = cc * t - ss * Z[i][1]; Z[i][1] = ss * t + cc * Z[i][1]; }
    }
}

__device__ inline void swap_cols(float Z[3][3], int a, int b) {
    if (a == 0 && b == 1) { for (int i = 0; i < 3; ++i) { float t = Z[i][0]; Z[i][0] = Z[i][1]; Z[i][1] = t; } }
    else if (a == 0 && b == 2) { for (int i = 0; i < 3; ++i) { float t = Z[i][0]; Z[i][0] = Z[i][2]; Z[i][2] = t; } }
    else { for (int i = 0; i < 3; ++i) { float t = Z[i][1]; Z[i][1] = Z[i][2]; Z[i][2] = t; } }
}

// faithful SSTEQR('I') for n=3 (1-based indices mirror the Fortran)
__device__ void steqr3(float d[3], float e[2], float Z[3][3]) {
#pragma clang fp contract(off)
    const float eps = 5.9604645e-08f;       // SLAMCH('E') = 2^-24
    const float eps2 = eps * eps;
    const float safmin = 1.17549435e-38f;   // 2^-126
    const float ssfmax = sqrtf(1.0f / safmin) / 3.0f;
    const float ssfmin = sqrtf(safmin) / eps2;
    const int n = 3;
    for (int r = 0; r < 3; ++r)
        for (int c = 0; c < 3; ++c) Z[r][c] = (r == c) ? 1.0f : 0.0f;
    const int nmaxit = n * 30;
    int jtot = 0;
    int l1 = 1;
    while (l1 <= n) {
        if (l1 > 1) e[l1 - 2] = 0.0f;
        int m = n;
        for (int mm_ = l1; mm_ <= n - 1; ++mm_) {
            float tst = fabsf(e[mm_ - 1]);
            if (tst == 0.0f) { m = mm_; break; }
            if (tst <= (sqrtf(fabsf(d[mm_ - 1])) * sqrtf(fabsf(d[mm_]))) * eps) {
                e[mm_ - 1] = 0.0f; m = mm_; break;
            }
        }
        int l = l1, lsv = l, lend = m, lendsv = lend;
        l1 = m + 1;
        if (lend == l) continue;
        float anorm = 0.0f;
        for (int i = l; i <= lend; ++i) anorm = fmaxf(anorm, fabsf(d[i - 1]));
        for (int i = l; i <= lend - 1; ++i) anorm = fmaxf(anorm, fabsf(e[i - 1]));
        int iscale = 0;
        if (anorm == 0.0f) continue;
        if (anorm > ssfmax) {
            iscale = 1; float sc = ssfmax / anorm;
            for (int i = l; i <= lend; ++i) d[i - 1] *= sc;
            for (int i = l; i <= lend - 1; ++i) e[i - 1] *= sc;
        } else if (anorm < ssfmin) {
            iscale = 2; float sc = ssfmin / anorm;
            for (int i = l; i <= lend; ++i) d[i - 1] *= sc;
            for (int i = l; i <= lend - 1; ++i) e[i - 1] *= sc;
        }
        if (fabsf(d[lend - 1]) < fabsf(d[l - 1])) { int t = l; l = lend; lend = t; }
        if (lend > l) {
            // ---- QL iteration ----
            for (;;) {
                int m2 = lend;
                if (l != lend) {
                    for (int i = l; i <= lend - 1; ++i) {
                        float tst = e[i - 1] * e[i - 1];
                        if (tst <= (eps2 * fabsf(d[i - 1])) * fabsf(d[i]) + safmin) { m2 = i; break; }
                    }
                }
                if (m2 < lend) e[m2 - 1] = 0.0f;
                float p = d[l - 1];
                if (m2 == l) { d[l - 1] = p; ++l; if (l <= lend) continue; break; }
                if (m2 == l + 1) {
                    float rt1, rt2, cc, ss;
                    slaev2_f(d[l - 1], e[l - 1], d[l], rt1, rt2, cc, ss);
                    rot_pair(Z, l - 1, cc, ss);
                    d[l - 1] = rt1; d[l] = rt2; e[l - 1] = 0.0f;
                    l += 2; if (l <= lend) continue; break;
                }
                if (jtot == nmaxit) break;
                ++jtot;
                float g = (d[l] - p) / (2.0f * e[l - 1]);
                float r = slapy2f(g, 1.0f);
                g = d[m2 - 1] - p + e[l - 1] / (g + copysignf(r, g));
                float s = 1.0f, c = 1.0f;
                p = 0.0f;
                float csv[2], ssv[2];
                for (int i = m2 - 1; i >= l; --i) {
                    float f = s * e[i - 1];
                    float b = c * e[i - 1];
                    slartg_f(g, f, c, s, r);
                    if (i != m2 - 1) e[i] = r;
                    g = d[i] - p;
                    r = (d[i - 1] - g) * s + 2.0f * c * b;
                    p = s * r;
                    d[i] = g + p;
                    g = c * r - b;
                    csv[i - l] = c; ssv[i - l] = -s;
                }
                int mmc = m2 - l + 1;
                for (int j = mmc - 1; j >= 1; --j) {
                    rot_pair(Z, (l - 1) + (j - 1), csv[j - 1], ssv[j - 1]);
                }
                d[l - 1] -= p;
                e[l - 1] = g;
            }
        } else {
            // ---- QR iteration ----
            for (;;) {
                int m2 = lend;
                if (l != lend) {
                    for (int i = l; i >= lend + 1; --i) {
                        float tst = e[i - 2] * e[i - 2];
                        if (tst <= (eps2 * fabsf(d[i - 1])) * fabsf(d[i - 2]) + safmin) { m2 = i; break; }
                    }
                }
                if (m2 > lend) e[m2 - 2] = 0.0f;
                float p = d[l - 1];
                if (m2 == l) { d[l - 1] = p; --l; if (l >= lend) continue; break; }
                if (m2 == l - 1) {
                    float rt1, rt2, cc, ss;
                    slaev2_f(d[l - 2], e[l - 2], d[l - 1], rt1, rt2, cc, ss);
                    rot_pair(Z, l - 2, cc, ss);
                    d[l - 2] = rt1; d[l - 1] = rt2; e[l - 2] = 0.0f;
                    l -= 2; if (l >= lend) continue; break;
                }
                if (jtot == nmaxit) break;
                ++jtot;
                float g = (d[l - 2] - p) / (2.0f * e[l - 2]);
                float r = slapy2f(g, 1.0f);
                g = d[m2 - 1] - p + e[l - 2] / (g + copysignf(r, g));
                float s = 1.0f, c = 1.0f;
                p = 0.0f;
                float csv[2], ssv[2];
                for (int i = m2; i <= l - 1; ++i) {
                    float f = s * e[i - 1];
                    float b = c * e[i - 1];
                    slartg_f(g, f, c, s, r);
                    if (i != m2) e[i - 2] = r;
                    g = d[i - 1] - p;
                    r = (d[i] - g) * s + 2.0f * c * b;
                    p = s * r;
                    d[i - 1] = g + p;
                    g = c * r - b;
                    csv[i - m2] = c; ssv[i - m2] = s;
                }
                int cnt = l - m2 + 1;
                for (int j = 1; j <= cnt - 1; ++j) {
                    rot_pair(Z, (m2 - 1) + (j - 1), csv[j - 1], ssv[j - 1]);
                }
                d[l - 1] -= p;
                e[l - 2] = g;
            }
        }
        if (iscale == 1) {
            float isc = anorm / ssfmax;
            for (int i = lsv; i <= lendsv; ++i) d[i - 1] *= isc;
            for (int i = lsv; i <= lendsv - 1; ++i) e[i - 1] *= isc;
        } else if (iscale == 2) {
            float isc = anorm / ssfmin;
            for (int i = lsv; i <= lendsv; ++i) d[i - 1] *= isc;
            for (int i = lsv; i <= lendsv - 1; ++i) e[i - 1] *= isc;
        }
        if (jtot >= nmaxit) break;
    }
    // selection-sort ascending with column swaps (SSTEQR label 160)
    for (int ii = 2; ii <= n; ++ii) {
        int i = ii - 1, kk = i;
        float p = d[i - 1];
        for (int j = ii; j <= n; ++j) if (d[j - 1] < p) { kk = j; p = d[j - 1]; }
        if (kk != i) { d[kk - 1] = d[i - 1]; d[i - 1] = p; swap_cols(Z, i - 1, kk - 1); }
    }
}

__global__ void eigen_kernel(const float* __restrict__ cov, float* __restrict__ out_n, int N) {
#pragma clang fp contract(off)
    int n = blockIdx.x * blockDim.x + threadIdx.x;
    if (n >= N) return;
    float a00 = cov[n * 6 + 0], a10 = cov[n * 6 + 1], a20 = cov[n * 6 + 2];
    float a11 = cov[n * 6 + 3], a21 = cov[n * 6 + 4], a22 = cov[n * 6 + 5];

    // SSYTD2 (lower), n=3. slarfg = Fortran (no FMA); ssymv/sdot/saxpy/ssyr2 =
    // OpenBLAS FMA kernels (every "+= a*b" fused).
    float tau = 0.0f, v2 = 0.0f, e0, d1, d2, e1;
    float xnorm = fabsf(a20);
    if (xnorm == 0.0f) { tau = 0.0f; v2 = 0.0f; e0 = a10; d1 = a11; d2 = a22; e1 = a21; }
    else {
        float beta = -copysignf(slapy2f(a10, xnorm), a10);
        tau = (beta - a10) / beta;
        float rinv = 1.0f / (a10 - beta);
        v2 = a20 * rinv;
        e0 = beta;
        float y1 = fmaf(tau, a21 * v2, tau * a11);
        float y2 = fmaf(tau * v2, a22, tau * a21);
        float dot = fmaf(y2, v2, y1);
        float al = -((0.5f * tau) * dot);
        float w1 = y1 + al;
        float w2 = fmaf(al, v2, y2);
        d1 = (a11 - w1) - w1;
        e1 = fmaf(v2, -w1, a21) - w2;
        d2 = fmaf(w2, -v2, fmaf(v2, -w2, a22));
    }
    float d[3] = { a00, d1, d2 };
    float e[2] = { e0, e1 };
    float Z[3][3];
    steqr3(d, e, Z);
    // SORMTR -> SORM2R -> SLARF: sgemv_t (FMA chain) + sger (FMA)
    if (tau != 0.0f) {
#pragma unroll
        for (int c2 = 0; c2 < 3; ++c2) {
            float sum = fmaf(Z[2][c2], v2, Z[1][c2]);
            float t = tau * sum;
            Z[1][c2] = Z[1][c2] - t;
            Z[2][c2] = fmaf(v2, -t, Z[2][c2]);
        }
    }
    // argsort(|lambda|) stable -> column of min |lambda|
    float A0 = fabsf(d[0]), A1 = fabsf(d[1]), A2 = fabsf(d[2]);
    int idx = 0; float best = A0;
    if (A1 < best) { idx = 1; best = A1; }
    if (A2 < best) { idx = 2; }
    float zx = (idx == 0) ? Z[0][0] : ((idx == 1) ? Z[0][1] : Z[0][2]);
    float zy = (idx == 0) ? Z[1][0] : ((idx == 1) ? Z[1][1] : Z[1][2]);
    float zz = (idx == 0) ? Z[2][0] : ((idx == 1) ? Z[2][1] : Z[2][2]);
    out_n[n * 3 + 0] = zx;
    out_n[n * 3 + 1] = zy;
    out_n[n * 3 + 2] = zz;
}

extern "C" void kernel_launch(void* const* d_in, const int* in_sizes, int n_in,
                              void* d_out, int out_size, void* d_ws, size_t ws_size,
                              hipStream_t stream) {
    const float* old_w = (const float*)d_in[0];
    const float* pos   = (const float*)d_in[1];
    const float* nrm   = (const float*)d_in[2];
    // d_in[3] edge_idx_l unused (redundant with dense_l)
    const int*   dense = (const int*)d_in[4];
    const float* sd    = (const float*)d_in[5];
    const float* W1    = (const float*)d_in[6];
    const float* b1    = (const float*)d_in[7];
    const float* W2    = (const float*)d_in[8];
    const float* b2    = (const float*)d_in[9];
    const float* W3    = (const float*)d_in[10];
    const float* b3    = (const float*)d_in[11];

    const int N = in_sizes[1] / 3;   // 50000
    float* ws = (float*)d_ws;
    float* cov = ws + COV_OFF;
    float* out_normals = (float*)d_out;           // N*3
    float* out_weights = (float*)d_out + N * 3;   // N*K

    prep_kernel<<<16, 256, 0, stream>>>(W1, W2, ws);
    gnn_kernel<<<(N + 7) / 8, 256, 0, stream>>>(old_w, pos, nrm, dense, sd, b1, b2,
                                                W3, b3, W2, ws, out_weights, cov, N);
    eigen_kernel<<<(N + 255) / 256, 256, 0, stream>>>(cov, out_normals, N);
}

// Round 16
// 277.534 us; speedup vs baseline: 2.9703x; 2.9703x over previous
//
#include <hip/hip_runtime.h>
#include <cmath>

#define KNB 32
#define HDIM 64

// ws layout (floats):
#define W1T_OFF 0                   // [64][6]  W1T[j][f] = W1[f][j]
#define W2BT_OFF (384 + 4096)       // [64][64] W2bT[j][i] = W2[64+i][j]
#define COV_OFF 8704                // [N][6]   f32 cov (c00,c10,c20,c11,c21,c22)

// ---------------- prep: transpose weights into ws ----------------
__global__ void prep_kernel(const float* __restrict__ W1, const float* __restrict__ W2,
                            float* __restrict__ ws) {
    int t = blockIdx.x * blockDim.x + threadIdx.x;
    if (t < 384) {
        int j = t / 6, f = t - j * 6;
        ws[W1T_OFF + t] = W1[f * HDIM + j];
    }
    if (t < 4096) {
        int j = t >> 6, i = t & 63;
        ws[W2BT_OFF + t] = W2[(HDIM + i) * HDIM + j];
    }
}

// numpy SIMD exp_FLOAT emulation (Cephes poly, FMA, rint quadrant, exact scale).
__device__ inline float numpy_expf(float x) {
#pragma clang fp contract(off)
    const float LOG2E = 1.44269504088896341f;
    const float C1 = 0.693359375f;              // ln2 hi (Cody-Waite)
    const float C2 = -2.12194440e-4f;           // ln2 lo
    float q = rintf(x * LOG2E);
    float r = fmaf(q, -C1, x);
    r = fmaf(q, -C2, r);
    float p = 1.9875691500e-4f;
    p = fmaf(p, r, 1.3981999507e-3f);
    p = fmaf(p, r, 8.3334519073e-3f);
    p = fmaf(p, r, 4.1665795894e-2f);
    p = fmaf(p, r, 1.6666665459e-1f);
    p = fmaf(p, r, 5.0000001201e-1f);
    float r2 = r * r;
    p = fmaf(r2, p, r);
    p = p + 1.0f;
    return ldexpf(p, (int)q);
}

// ---------------- MLP + weights + cov ----------------
// R16 = R13 (best config: 273 us; outer-product 4x16 tiles, W2 via s_load)
// + __syncthreads() per jb tile: the block's 4 waves walk the 16 KB W2
// scalar stream in LOCKSTEP, so each 4 KB tile is K$-fetched once and hit
// by the other 3 waves (R13's ~45% issue rate attributed to K$ LRU-thrash:
// 13.6 uncorrelated wave streams vs ~16 KB scalar cache).
// Broadcast-path ranking measured R13/R14/R15: scalar 273 < DS 316 < vector 824.
// Numerics: barriers only -> bit-exact vs R13.
__global__ __launch_bounds__(256)
void gnn_kernel(const float* __restrict__ old_w, const float* __restrict__ pos,
                const float* __restrict__ nrm, const int* __restrict__ dense,
                const float* __restrict__ sd_p, const float* __restrict__ b1,
                const float* __restrict__ b2, const float* __restrict__ W3,
                const float* __restrict__ b3, const float* __restrict__ W2orig,
                const float* __restrict__ wsW,
                float* __restrict__ out_w, float* __restrict__ cov_out, int N)
{
#pragma clang fp contract(off)
    const int wave = threadIdx.x >> 6;
    const int lane = threadIdx.x & 63;
    const int half = lane >> 5;
    const int k = lane & 31;
    const int pt_slot = wave * 2 + half;
    const int n = blockIdx.x * 8 + pt_slot;
    const bool valid = (n < N);
    const int nn = valid ? n : 0;

    __shared__ float aggterm_s[8][HDIM];
    __shared__ float edat[8][KNB][4];   // rx,ry,rz,w per edge

    // ---- phase 1: per-edge features (numpy evaluation order, no contraction) ----
    int idx = dense[nn * KNB + k];
    float px = pos[nn * 3 + 0], py = pos[nn * 3 + 1], pz = pos[nn * 3 + 2];
    float rx = pos[idx * 3 + 0] - px;
    float ry = pos[idx * 3 + 1] - py;
    float rz = pos[idx * 3 + 2] - pz;
    float dist = sqrtf((rx * rx + ry * ry) + rz * rz);
    float nx = nrm[nn * 3 + 0], ny = nrm[nn * 3 + 1], nz = nrm[nn * 3 + 2];
    float ndot = fabsf((nx * rx + ny * ry) + nz * rz) / (dist + 1e-8f);
    float sd = sd_p[0];
    float f0 = rx / sd, f1 = ry / sd, f2 = rz / sd, f3 = dist / sd;
    float f4 = ndot, f5 = old_w[nn * KNB + k];

    // ---- phase 2: h[j] = relu(feat @ W1 + b1), K=6 FMA chain, bias after ----
    float h[HDIM];
#pragma unroll
    for (int j = 0; j < HDIM; ++j) {
        const float* w1r = wsW + W1T_OFF + j * 6;   // uniform -> s_load
        float a = f0 * w1r[0];
        a = fmaf(f1, w1r[1], a);
        a = fmaf(f2, w1r[2], a);
        a = fmaf(f3, w1r[3], a);
        a = fmaf(f4, w1r[4], a);
        a = fmaf(f5, w1r[5], a);
        a = a + b1[j];
        h[j] = fmaxf(a, 0.0f);
    }

    // ---- fused agg-reduce + cooperative aggterm (lane k -> j=k, k+32) ----
    {
        float t0 = 0.0f, t1 = 0.0f;
        const float4* r0 = (const float4*)(wsW + W2BT_OFF + k * HDIM);
        const float4* r1 = (const float4*)(wsW + W2BT_OFF + (k + 32) * HDIM);
#pragma unroll
        for (int i4 = 0; i4 < HDIM / 4; ++i4) {
            float4 a0 = r0[i4], a1 = r1[i4];
#pragma unroll
            for (int t = 0; t < 4; ++t) {
                float m = h[4 * i4 + t];
                m = fmaxf(m, __shfl_xor(m, 1, 64));
                m = fmaxf(m, __shfl_xor(m, 2, 64));
                m = fmaxf(m, __shfl_xor(m, 4, 64));
                m = fmaxf(m, __shfl_xor(m, 8, 64));
                m = fmaxf(m, __shfl_xor(m, 16, 64));
                float w0 = (t == 0) ? a0.x : (t == 1) ? a0.y : (t == 2) ? a0.z : a0.w;
                float w1v = (t == 0) ? a1.x : (t == 1) ? a1.y : (t == 2) ? a1.z : a1.w;
                t0 = fmaf(m, w0, t0);
                t1 = fmaf(m, w1v, t1);
            }
        }
        aggterm_s[pt_slot][k] = t0;
        aggterm_s[pt_slot][k + 32] = t1;
    }
    // written and read by the same 32-lane half; compiler's lgkmcnt orders it.

    // ---- phase 3: outer-product tiles; waves barrier-locked per jb tile so
    //      the 4 waves' identical 4 KB s_load streams coalesce in the K$ ----
    float pv = 0.0f;
    const float* atrow = aggterm_s[pt_slot];
    for (int jb = 0; jb < 4; ++jb) {
        __syncthreads();                           // lockstep the W2 stream
        const float* w2base = W2orig + jb * 16;
        float acc16[16];
        {
            const float* w2r = w2base;                 // i = 0 row
#pragma unroll
            for (int jj = 0; jj < 16; ++jj) acc16[jj] = h[0] * w2r[jj];
        }
#pragma unroll
        for (int i = 1; i < HDIM; ++i) {
            const float* w2r = w2base + i * HDIM;      // uniform -> s_load_dwordx16
            float hi = h[i];
#pragma unroll
            for (int jj = 0; jj < 16; ++jj) acc16[jj] = fmaf(hi, w2r[jj], acc16[jj]);
        }
#pragma unroll
        for (int jj = 0; jj < 16; ++jj) {
            int j = jb * 16 + jj;
            float a = (acc16[jj] + atrow[j]) + b2[j];
            float h2 = fmaxf(a, 0.0f);
            pv = fmaf(h2, W3[j], pv);
        }
    }
    float t = -(pv + b3[0]);
    float wk = 1.0f / (1.0f + numpy_expf(t));
    if (valid) out_w[nn * KNB + k] = wk;

    // ---- cov in numpy-einsum order, lower-triangle product order ----
    edat[pt_slot][k][0] = rx;
    edat[pt_slot][k][1] = ry;
    edat[pt_slot][k][2] = rz;
    edat[pt_slot][k][3] = wk;
    __syncthreads();
    if (valid && k < 6) {
        const int EI[6] = {0, 1, 2, 1, 2, 2};
        const int EJ[6] = {0, 0, 0, 1, 1, 2};
        int ei = EI[k], ej = EJ[k];
        float acc = 0.0f;
        for (int kk = 0; kk < KNB; ++kk) {
            float w = edat[pt_slot][kk][3];
            acc = acc + (w * edat[pt_slot][kk][ei]) * edat[pt_slot][kk][ej];
        }
        cov_out[n * 6 + k] = acc;
    }
}

// ================= LAPACK-faithful SINGLE-PRECISION 3x3 eigensolver =================
// Model: LAPACK Fortran (ssteqr/slaev2/slartg/slarfg) = baseline x86-64, NO FMA
// (contract off, mul+add). BLAS kernels called by ssytd2/slarf (ssymv, sdot,
// saxpy, ssyr2, sgemv, sger) = OpenBLAS arch-dispatched C kernels compiled with
// -mfma -ffp-contract=fast: every "acc += a*b" is an FMA. slartg >= 3.10.

__device__ inline float slapy2f(float x, float y) {
#pragma clang fp contract(off)
    float ax = fabsf(x), ay = fabsf(y);
    float w = fmaxf(ax, ay), z = fminf(ax, ay);
    if (z == 0.0f) return w;
    float q = z / w;
    return w * sqrtf(1.0f + q * q);
}

// LAPACK >= 3.10 slartg (f32, moderate-magnitude path)
__device__ inline void slartg_f(float f, float g, float& c, float& s, float& r) {
#pragma clang fp contract(off)
    if (g == 0.0f) { c = 1.0f; s = 0.0f; r = f; }
    else if (f == 0.0f) { c = 0.0f; s = copysignf(1.0f, g); r = fabsf(g); }
    else {
        float d = sqrtf(f * f + g * g);
        c = fabsf(f) / d;
        r = copysignf(d, f);
        s = g / r;
    }
}

__device__ void slaev2_f(float a, float b, float c, float& rt1, float& rt2,
                         float& cs1, float& sn1) {
#pragma clang fp contract(off)
    float sm = a + c, df = a - c, adf = fabsf(df), tb = b + b, ab = fabsf(tb);
    float acmx, acmn;
    if (fabsf(a) > fabsf(c)) { acmx = a; acmn = c; } else { acmx = c; acmn = a; }
    float rt;
    if (adf > ab)      { float q = ab / adf; rt = adf * sqrtf(1.0f + q * q); }
    else if (adf < ab) { float q = adf / ab; rt = ab * sqrtf(1.0f + q * q); }
    else               { rt = ab * sqrtf(2.0f); }
    int sgn1;
    if (sm < 0.0f)      { rt1 = 0.5f * (sm - rt); sgn1 = -1; rt2 = (acmx / rt1) * acmn - (b / rt1) * b; }
    else if (sm > 0.0f) { rt1 = 0.5f * (sm + rt); sgn1 = 1;  rt2 = (acmx / rt1) * acmn - (b / rt1) * b; }
    else                { rt1 = 0.5f * rt; rt2 = -0.5f * rt; sgn1 = 1; }
    float cs; int sgn2;
    if (df >= 0.0f) { cs = df + rt; sgn2 = 1; } else { cs = df - rt; sgn2 = -1; }
    float acs = fabsf(cs);
    if (acs > ab) { float ct = -tb / cs; sn1 = 1.0f / sqrtf(1.0f + ct * ct); cs1 = ct * sn1; }
    else {
        if (ab == 0.0f) { cs1 = 1.0f; sn1 = 0.0f; }
        else { float tn = -cs / tb; cs1 = 1.0f / sqrtf(1.0f + tn * tn); sn1 = tn * cs1; }
    }
    if (sgn1 == sgn2) { float tn = cs1; cs1 = -sn1; sn1 = tn; }
}

// apply right rotation to Z columns (ca, ca+1) per SLASR 'R','V' (identity-skip)
__device__ inline void rot_pair(float Z[3][3], int ca, float cc, float ss) {
#pragma clang fp contract(off)
    if (cc == 1.0f && ss == 0.0f) return;
    if (ca == 0) {
#pragma unroll
        for (int i = 0; i < 3; ++i) { float t = Z[i][1]; Z[i][1] = cc * t - ss * Z[i][0]; Z[i][0] = ss * t + cc * Z[i][0]; }
    } else {
#pragma unroll
        for (int i = 0; i < 3; ++i) { float t = Z[i][2]; Z[i][2] = cc * t - ss * Z[i][1]; Z[i][1] = ss * t + cc * Z[i][1]; }
    }
}

__device__ inline void swap_cols(float Z[3][3], int a, int b) {
    if (a == 0 && b == 1) { for (int i = 0; i < 3; ++i) { float t = Z[i][0]; Z[i][0] = Z[i][1]; Z[i][1] = t; } }
    else if (a == 0 && b == 2) { for (int i = 0; i < 3; ++i) { float t = Z[i][0]; Z[i][0] = Z[i][2]; Z[i][2] = t; } }
    else { for (int i = 0; i < 3; ++i) { float t = Z[i][1]; Z[i][1] = Z[i][2]; Z[i][2] = t; } }
}

// faithful SSTEQR('I') for n=3 (1-based indices mirror the Fortran)
__device__ void steqr3(float d[3], float e[2], float Z[3][3]) {
#pragma clang fp contract(off)
    const float eps = 5.9604645e-08f;       // SLAMCH('E') = 2^-24
    const float eps2 = eps * eps;
    const float safmin = 1.17549435e-38f;   // 2^-126
    const float ssfmax = sqrtf(1.0f / safmin) / 3.0f;
    const float ssfmin = sqrtf(safmin) / eps2;
    const int n = 3;
    for (int r = 0; r < 3; ++r)
        for (int c = 0; c < 3; ++c) Z[r][c] = (r == c) ? 1.0f : 0.0f;
    const int nmaxit = n * 30;
    int jtot = 0;
    int l1 = 1;
    while (l1 <= n) {
        if (l1 > 1) e[l1 - 2] = 0.0f;
        int m = n;
        for (int mm_ = l1; mm_ <= n - 1; ++mm_) {
            float tst = fabsf(e[mm_ - 1]);
            if (tst == 0.0f) { m = mm_; break; }
            if (tst <= (sqrtf(fabsf(d[mm_ - 1])) * sqrtf(fabsf(d[mm_]))) * eps) {
                e[mm_ - 1] = 0.0f; m = mm_; break;
            }
        }
        int l = l1, lsv = l, lend = m, lendsv = lend;
        l1 = m + 1;
        if (lend == l) continue;
        float anorm = 0.0f;
        for (int i = l; i <= lend; ++i) anorm = fmaxf(anorm, fabsf(d[i - 1]));
        for (int i = l; i <= lend - 1; ++i) anorm = fmaxf(anorm, fabsf(e[i - 1]));
        int iscale = 0;
        if (anorm == 0.0f) continue;
        if (anorm > ssfmax) {
            iscale = 1; float sc = ssfmax / anorm;
            for (int i = l; i <= lend; ++i) d[i - 1] *= sc;
            for (int i = l; i <= lend - 1; ++i) e[i - 1] *= sc;
        } else if (anorm < ssfmin) {
            iscale = 2; float sc = ssfmin / anorm;
            for (int i = l; i <= lend; ++i) d[i - 1] *= sc;
            for (int i = l; i <= lend - 1; ++i) e[i - 1] *= sc;
        }
        if (fabsf(d[lend - 1]) < fabsf(d[l - 1])) { int t = l; l = lend; lend = t; }
        if (lend > l) {
            // ---- QL iteration ----
            for (;;) {
                int m2 = lend;
                if (l != lend) {
                    for (int i = l; i <= lend - 1; ++i) {
                        float tst = e[i - 1] * e[i - 1];
                        if (tst <= (eps2 * fabsf(d[i - 1])) * fabsf(d[i]) + safmin) { m2 = i; break; }
                    }
                }
                if (m2 < lend) e[m2 - 1] = 0.0f;
                float p = d[l - 1];
                if (m2 == l) { d[l - 1] = p; ++l; if (l <= lend) continue; break; }
                if (m2 == l + 1) {
                    float rt1, rt2, cc, ss;
                    slaev2_f(d[l - 1], e[l - 1], d[l], rt1, rt2, cc, ss);
                    rot_pair(Z, l - 1, cc, ss);
                    d[l - 1] = rt1; d[l] = rt2; e[l - 1] = 0.0f;
                    l += 2; if (l <= lend) continue; break;
                }
                if (jtot == nmaxit) break;
                ++jtot;
                float g = (d[l] - p) / (2.0f * e[l - 1]);
                float r = slapy2f(g, 1.0f);
                g = d[m2 - 1] - p + e[l - 1] / (g + copysignf(r, g));
                float s = 1.0f, c = 1.0f;
                p = 0.0f;
                float csv[2], ssv[2];
                for (int i = m2 - 1; i >= l; --i) {
                    float f = s * e[i - 1];
                    float b = c * e[i - 1];
                    slartg_f(g, f, c, s, r);
                    if (i != m2 - 1) e[i] = r;
                    g = d[i] - p;
                    r = (d[i - 1] - g) * s + 2.0f * c * b;
                    p = s * r;
                    d[i] = g + p;
                    g = c * r - b;
                    csv[i - l] = c; ssv[i - l] = -s;
                }
                int mmc = m2 - l + 1;
                for (int j = mmc - 1; j >= 1; --j) {
                    rot_pair(Z, (l - 1) + (j - 1), csv[j - 1], ssv[j - 1]);
                }
                d[l - 1] -= p;
                e[l - 1] = g;
            }
        } else {
            // ---- QR iteration ----
            for (;;) {
                int m2 = lend;
                if (l != lend) {
                    for (int i = l; i >= lend + 1; --i) {
                        float tst = e[i - 2] * e[i - 2];
                        if (tst <= (eps2 * fabsf(d[i - 1])) * fabsf(d[i - 2]) + safmin) { m2 = i; break; }
                    }
                }
                if (m2 > lend) e[m2 - 2] = 0.0f;
                float p = d[l - 1];
                if (m2 == l) { d[l - 1] = p; --l; if (l >= lend) continue; break; }
                if (m2 == l - 1) {
                    float rt1, rt2, cc, ss;
                    slaev2_f(d[l - 2], e[l - 2], d[l - 1], rt1, rt2, cc, ss);
                    rot_pair(Z, l - 2, cc, ss);
                    d[l - 2] = rt1; d[l - 1] = rt2; e[l - 2] = 0.0f;
                    l -= 2; if (l >= lend) continue; break;
                }
                if (jtot == nmaxit) break;
                ++jtot;
                float g = (d[l - 2] - p) / (2.0f * e[l - 2]);
                float r = slapy2f(g, 1.0f);
                g = d[m2 - 1] - p + e[l - 2] / (g + copysignf(r, g));
                float s = 1.0f, c = 1.0f;
                p = 0.0f;
                float csv[2], ssv[2];
                for (int i = m2; i <= l - 1; ++i) {
                    float f = s * e[i - 1];
                    float b = c * e[i - 1];
                    slartg_f(g, f, c, s, r);
                    if (i != m2) e[i - 2] = r;
                    g = d[i - 1] - p;
                    r = (d[i] - g) * s + 2.0f * c * b;
                    p = s * r;
                    d[i - 1] = g + p;
                    g = c * r - b;
                    csv[i - m2] = c; ssv[i - m2] = s;
                }
                int cnt = l - m2 + 1;
                for (int j = 1; j <= cnt - 1; ++j) {
                    rot_pair(Z, (m2 - 1) + (j - 1), csv[j - 1], ssv[j - 1]);
                }
                d[l - 1] -= p;
                e[l - 2] = g;
            }
        }
        if (iscale == 1) {
            float isc = anorm / ssfmax;
            for (int i = lsv; i <= lendsv; ++i) d[i - 1] *= isc;
            for (int i = lsv; i <= lendsv - 1; ++i) e[i - 1] *= isc;
        } else if (iscale == 2) {
            float isc = anorm / ssfmin;
            for (int i = lsv; i <= lendsv; ++i) d[i - 1] *= isc;
            for (int i = lsv; i <= lendsv - 1; ++i) e[i - 1] *= isc;
        }
        if (jtot >= nmaxit) break;
    }
    // selection-sort ascending with column swaps (SSTEQR label 160)
    for (int ii = 2; ii <= n; ++ii) {
        int i = ii - 1, kk = i;
        float p = d[i - 1];
        for (int j = ii; j <= n; ++j) if (d[j - 1] < p) { kk = j; p = d[j - 1]; }
        if (kk != i) { d[kk - 1] = d[i - 1]; d[i - 1] = p; swap_cols(Z, i - 1, kk - 1); }
    }
}

__global__ void eigen_kernel(const float* __restrict__ cov, float* __restrict__ out_n, int N) {
#pragma clang fp contract(off)
    int n = blockIdx.x * blockDim.x + threadIdx.x;
    if (n >= N) return;
    float a00 = cov[n * 6 + 0], a10 = cov[n * 6 + 1], a20 = cov[n * 6 + 2];
    float a11 = cov[n * 6 + 3], a21 = cov[n * 6 + 4], a22 = cov[n * 6 + 5];

    // SSYTD2 (lower), n=3. slarfg = Fortran (no FMA); ssymv/sdot/saxpy/ssyr2 =
    // OpenBLAS FMA kernels (every "+= a*b" fused).
    float tau = 0.0f, v2 = 0.0f, e0, d1, d2, e1;
    float xnorm = fabsf(a20);
    if (xnorm == 0.0f) { tau = 0.0f; v2 = 0.0f; e0 = a10; d1 = a11; d2 = a22; e1 = a21; }
    else {
        float beta = -copysignf(slapy2f(a10, xnorm), a10);
        tau = (beta - a10) / beta;
        float rinv = 1.0f / (a10 - beta);
        v2 = a20 * rinv;
        e0 = beta;
        float y1 = fmaf(tau, a21 * v2, tau * a11);
        float y2 = fmaf(tau * v2, a22, tau * a21);
        float dot = fmaf(y2, v2, y1);
        float al = -((0.5f * tau) * dot);
        float w1 = y1 + al;
        float w2 = fmaf(al, v2, y2);
        d1 = (a11 - w1) - w1;
        e1 = fmaf(v2, -w1, a21) - w2;
        d2 = fmaf(w2, -v2, fmaf(v2, -w2, a22));
    }
    float d[3] = { a00, d1, d2 };
    float e[2] = { e0, e1 };
    float Z[3][3];
    steqr3(d, e, Z);
    // SORMTR -> SORM2R -> SLARF: sgemv_t (FMA chain) + sger (FMA)
    if (tau != 0.0f) {
#pragma unroll
        for (int c2 = 0; c2 < 3; ++c2) {
            float sum = fmaf(Z[2][c2], v2, Z[1][c2]);
            float t = tau * sum;
            Z[1][c2] = Z[1][c2] - t;
            Z[2][c2] = fmaf(v2, -t, Z[2][c2]);
        }
    }
    // argsort(|lambda|) stable -> column of min |lambda|
    float A0 = fabsf(d[0]), A1 = fabsf(d[1]), A2 = fabsf(d[2]);
    int idx = 0; float best = A0;
    if (A1 < best) { idx = 1; best = A1; }
    if (A2 < best) { idx = 2; }
    float zx = (idx == 0) ? Z[0][0] : ((idx == 1) ? Z[0][1] : Z[0][2]);
    float zy = (idx == 0) ? Z[1][0] : ((idx == 1) ? Z[1][1] : Z[1][2]);
    float zz = (idx == 0) ? Z[2][0] : ((idx == 1) ? Z[2][1] : Z[2][2]);
    out_n[n * 3 + 0] = zx;
    out_n[n * 3 + 1] = zy;
    out_n[n * 3 + 2] = zz;
}

extern "C" void kernel_launch(void* const* d_in, const int* in_sizes, int n_in,
                              void* d_out, int out_size, void* d_ws, size_t ws_size,
                              hipStream_t stream) {
    const float* old_w = (const float*)d_in[0];
    const float* pos   = (const float*)d_in[1];
    const float* nrm   = (const float*)d_in[2];
    // d_in[3] edge_idx_l unused (redundant with dense_l)
    const int*   dense = (const int*)d_in[4];
    const float* sd    = (const float*)d_in[5];
    const float* W1    = (const float*)d_in[6];
    const float* b1    = (const float*)d_in[7];
    const float* W2    = (const float*)d_in[8];
    const float* b2    = (const float*)d_in[9];
    const float* W3    = (const float*)d_in[10];
    const float* b3    = (const float*)d_in[11];

    const int N = in_sizes[1] / 3;   // 50000
    float* ws = (float*)d_ws;
    float* cov = ws + COV_OFF;
    float* out_normals = (float*)d_out;           // N*3
    float* out_weights = (float*)d_out + N * 3;   // N*K

    prep_kernel<<<16, 256, 0, stream>>>(W1, W2, ws);
    gnn_kernel<<<(N + 7) / 8, 256, 0, stream>>>(old_w, pos, nrm, dense, sd, b1, b2,
                                                W3, b3, W2, ws, out_weights, cov, N);
    eigen_kernel<<<(N + 255) / 256, 256, 0, stream>>>(cov, out_normals, N);
}

// Round 17
// 213.014 us; speedup vs baseline: 3.8700x; 1.3029x over previous
//
#include <hip/hip_runtime.h>
#include <cmath>

#define KNB 32
#define HDIM 64

// ws layout (floats):
#define W1R8_OFF 0                  // [64][8]  row i = {W1[0..5][i], b1[i], 0}
#define COV_OFF 8704                // [N][6]   f32 cov (c00,c10,c20,c11,c21,c22)

// ---------------- prep: pack W1 rows (+b1) into ws ----------------
__global__ void prep_kernel(const float* __restrict__ W1, const float* __restrict__ b1,
                            float* __restrict__ ws) {
    int t = blockIdx.x * blockDim.x + threadIdx.x;
    if (t < 512) {
        int row = t >> 3, c = t & 7;
        float v = (c < 6) ? W1[c * HDIM + row] : ((c == 6) ? b1[row] : 0.0f);
        ws[W1R8_OFF + t] = v;
    }
}

// numpy SIMD exp_FLOAT emulation (Cephes poly, FMA, rint quadrant, exact scale).
__device__ inline float numpy_expf(float x) {
#pragma clang fp contract(off)
    const float LOG2E = 1.44269504088896341f;
    const float C1 = 0.693359375f;              // ln2 hi (Cody-Waite)
    const float C2 = -2.12194440e-4f;           // ln2 lo
    float q = rintf(x * LOG2E);
    float r = fmaf(q, -C1, x);
    r = fmaf(q, -C2, r);
    float p = 1.9875691500e-4f;
    p = fmaf(p, r, 1.3981999507e-3f);
    p = fmaf(p, r, 8.3334519073e-3f);
    p = fmaf(p, r, 4.1665795894e-2f);
    p = fmaf(p, r, 1.6666665459e-1f);
    p = fmaf(p, r, 5.0000001201e-1f);
    float r2 = r * r;
    p = fmaf(r2, p, r);
    p = p + 1.0f;
    return ldexpf(p, (int)q);
}

// ---------------- MLP + weights + cov ----------------
// R17: FUSED single i-pass. h_i is computed from the W1 row, shfl-reduced,
// FMA'd into all 64 acc chains + 2 aggterm chains, then DISCARDED — the h[64]
// array (which the compiler had pushed into AGPRs, capping occupancy at
// ~3.4 waves/SIMD and adding accvgpr round-trips) no longer exists.
// Aggterm reads W2's second half COALESCED from the original layout
// (lane k -> W2[64+i][k], consecutive dwords). launch_bounds(256,4) caps
// unified regs at 128 (est. ~90 live) -> ~4+ waves/SIMD.
// Bit-exactness: every per-element FMA chain keeps R13's exact op order
// (acc[j]: mul at i=0 peeled, fmaf i ascending; t0/t1: fmaf i ascending,
// same W2 bits; pv: j ascending; h_i chain unchanged; max reduce order-free).
__global__ __launch_bounds__(256, 4)
void gnn_kernel(const float* __restrict__ old_w, const float* __restrict__ pos,
                const float* __restrict__ nrm, const int* __restrict__ dense,
                const float* __restrict__ sd_p, const float* __restrict__ b2,
                const float* __restrict__ W3, const float* __restrict__ b3,
                const float* __restrict__ W2orig, const float* __restrict__ wsW,
                float* __restrict__ out_w, float* __restrict__ cov_out, int N)
{
#pragma clang fp contract(off)
    const int wave = threadIdx.x >> 6;
    const int lane = threadIdx.x & 63;
    const int half = lane >> 5;
    const int k = lane & 31;
    const int pt_slot = wave * 2 + half;
    const int n = blockIdx.x * 8 + pt_slot;
    const bool valid = (n < N);
    const int nn = valid ? n : 0;

    __shared__ float aggterm_s[8][HDIM];
    __shared__ float edat[8][KNB][4];   // rx,ry,rz,w per edge

    // ---- phase 1: per-edge features (numpy evaluation order, no contraction) ----
    int idx = dense[nn * KNB + k];
    float px = pos[nn * 3 + 0], py = pos[nn * 3 + 1], pz = pos[nn * 3 + 2];
    float rx = pos[idx * 3 + 0] - px;
    float ry = pos[idx * 3 + 1] - py;
    float rz = pos[idx * 3 + 2] - pz;
    float dist = sqrtf((rx * rx + ry * ry) + rz * rz);
    float nx = nrm[nn * 3 + 0], ny = nrm[nn * 3 + 1], nz = nrm[nn * 3 + 2];
    float ndot = fabsf((nx * rx + ny * ry) + nz * rz) / (dist + 1e-8f);
    float sd = sd_p[0];
    float f0 = rx / sd, f1 = ry / sd, f2 = rz / sd, f3 = dist / sd;
    float f4 = ndot, f5 = old_w[nn * KNB + k];

    // ---- fused phases 2+3: one pass over i = 0..63 ----
    float acc[HDIM];
    float t0 = 0.0f, t1 = 0.0f;
    const float* w2b0 = W2orig + HDIM * HDIM + k;        // W2[64+i][k]
    const float* w2b1 = W2orig + HDIM * HDIM + k + 32;   // W2[64+i][k+32]

    // i = 0 peeled (acc init via mul, exactly like R13's i=0 row)
    {
        const float* w1r = wsW + W1R8_OFF;               // uniform -> s_load
        float a = f0 * w1r[0];
        a = fmaf(f1, w1r[1], a);
        a = fmaf(f2, w1r[2], a);
        a = fmaf(f3, w1r[3], a);
        a = fmaf(f4, w1r[4], a);
        a = fmaf(f5, w1r[5], a);
        a = a + w1r[6];                                  // + b1[0]
        float hi = fmaxf(a, 0.0f);
        float m = hi;
        m = fmaxf(m, __shfl_xor(m, 1, 64));
        m = fmaxf(m, __shfl_xor(m, 2, 64));
        m = fmaxf(m, __shfl_xor(m, 4, 64));
        m = fmaxf(m, __shfl_xor(m, 8, 64));
        m = fmaxf(m, __shfl_xor(m, 16, 64));
        t0 = fmaf(m, w2b0[0], t0);
        t1 = fmaf(m, w2b1[0], t1);
        const float* w2r = W2orig;                       // uniform -> s_load_dwordx16
#pragma unroll
        for (int jj = 0; jj < HDIM; ++jj) acc[jj] = hi * w2r[jj];
    }
#pragma unroll 3
    for (int i = 1; i < HDIM; ++i) {
        const float* w1r = wsW + W1R8_OFF + i * 8;       // uniform -> s_load_dwordx8
        float a = f0 * w1r[0];
        a = fmaf(f1, w1r[1], a);
        a = fmaf(f2, w1r[2], a);
        a = fmaf(f3, w1r[3], a);
        a = fmaf(f4, w1r[4], a);
        a = fmaf(f5, w1r[5], a);
        a = a + w1r[6];                                  // + b1[i]
        float hi = fmaxf(a, 0.0f);
        float m = hi;
        m = fmaxf(m, __shfl_xor(m, 1, 64));
        m = fmaxf(m, __shfl_xor(m, 2, 64));
        m = fmaxf(m, __shfl_xor(m, 4, 64));
        m = fmaxf(m, __shfl_xor(m, 8, 64));
        m = fmaxf(m, __shfl_xor(m, 16, 64));
        t0 = fmaf(m, w2b0[i * HDIM], t0);                // coalesced vector load
        t1 = fmaf(m, w2b1[i * HDIM], t1);
        const float* w2r = W2orig + i * HDIM;            // uniform -> s_load_dwordx16
#pragma unroll
        for (int jj = 0; jj < HDIM; ++jj) acc[jj] = fmaf(hi, w2r[jj], acc[jj]);
    }
    aggterm_s[pt_slot][k] = t0;
    aggterm_s[pt_slot][k + 32] = t1;
    // written and read by the same 32-lane half; compiler's lgkmcnt orders it.

    // ---- epilogue: h2[j] = relu((acc+atrow)+b2); pv chain j ascending ----
    float pv = 0.0f;
    const float* atrow = aggterm_s[pt_slot];
#pragma unroll
    for (int j = 0; j < HDIM; ++j) {
        float a = (acc[j] + atrow[j]) + b2[j];
        float h2 = fmaxf(a, 0.0f);
        pv = fmaf(h2, W3[j], pv);
    }
    float t = -(pv + b3[0]);
    float wk = 1.0f / (1.0f + numpy_expf(t));
    if (valid) out_w[nn * KNB + k] = wk;

    // ---- cov in numpy-einsum order, lower-triangle product order ----
    edat[pt_slot][k][0] = rx;
    edat[pt_slot][k][1] = ry;
    edat[pt_slot][k][2] = rz;
    edat[pt_slot][k][3] = wk;
    __syncthreads();
    if (valid && k < 6) {
        const int EI[6] = {0, 1, 2, 1, 2, 2};
        const int EJ[6] = {0, 0, 0, 1, 1, 2};
        int ei = EI[k], ej = EJ[k];
        float acc2 = 0.0f;
        for (int kk = 0; kk < KNB; ++kk) {
            float w = edat[pt_slot][kk][3];
            acc2 = acc2 + (w * edat[pt_slot][kk][ei]) * edat[pt_slot][kk][ej];
        }
        cov_out[n * 6 + k] = acc2;
    }
}

// ================= LAPACK-faithful SINGLE-PRECISION 3x3 eigensolver =================
// Model: LAPACK Fortran (ssteqr/slaev2/slartg/slarfg) = baseline x86-64, NO FMA
// (contract off, mul+add). BLAS kernels called by ssytd2/slarf (ssymv, sdot,
// saxpy, ssyr2, sgemv, sger) = OpenBLAS arch-dispatched C kernels compiled with
// -mfma -ffp-contract=fast: every "acc += a*b" is an FMA. slartg >= 3.10.

__device__ inline float slapy2f(float x, float y) {
#pragma clang fp contract(off)
    float ax = fabsf(x), ay = fabsf(y);
    float w = fmaxf(ax, ay), z = fminf(ax, ay);
    if (z == 0.0f) return w;
    float q = z / w;
    return w * sqrtf(1.0f + q * q);
}

// LAPACK >= 3.10 slartg (f32, moderate-magnitude path)
__device__ inline void slartg_f(float f, float g, float& c, float& s, float& r) {
#pragma clang fp contract(off)
    if (g == 0.0f) { c = 1.0f; s = 0.0f; r = f; }
    else if (f == 0.0f) { c = 0.0f; s = copysignf(1.0f, g); r = fabsf(g); }
    else {
        float d = sqrtf(f * f + g * g);
        c = fabsf(f) / d;
        r = copysignf(d, f);
        s = g / r;
    }
}

__device__ void slaev2_f(float a, float b, float c, float& rt1, float& rt2,
                         float& cs1, float& sn1) {
#pragma clang fp contract(off)
    float sm = a + c, df = a - c, adf = fabsf(df), tb = b + b, ab = fabsf(tb);
    float acmx, acmn;
    if (fabsf(a) > fabsf(c)) { acmx = a; acmn = c; } else { acmx = c; acmn = a; }
    float rt;
    if (adf > ab)      { float q = ab / adf; rt = adf * sqrtf(1.0f + q * q); }
    else if (adf < ab) { float q = adf / ab; rt = ab * sqrtf(1.0f + q * q); }
    else               { rt = ab * sqrtf(2.0f); }
    int sgn1;
    if (sm < 0.0f)      { rt1 = 0.5f * (sm - rt); sgn1 = -1; rt2 = (acmx / rt1) * acmn - (b / rt1) * b; }
    else if (sm > 0.0f) { rt1 = 0.5f * (sm + rt); sgn1 = 1;  rt2 = (acmx / rt1) * acmn - (b / rt1) * b; }
    else                { rt1 = 0.5f * rt; rt2 = -0.5f * rt; sgn1 = 1; }
    float cs; int sgn2;
    if (df >= 0.0f) { cs = df + rt; sgn2 = 1; } else { cs = df - rt; sgn2 = -1; }
    float acs = fabsf(cs);
    if (acs > ab) { float ct = -tb / cs; sn1 = 1.0f / sqrtf(1.0f + ct * ct); cs1 = ct * sn1; }
    else {
        if (ab == 0.0f) { cs1 = 1.0f; sn1 = 0.0f; }
        else { float tn = -cs / tb; cs1 = 1.0f / sqrtf(1.0f + tn * tn); sn1 = tn * cs1; }
    }
    if (sgn1 == sgn2) { float tn = cs1; cs1 = -sn1; sn1 = tn; }
}

// apply right rotation to Z columns (ca, ca+1) per SLASR 'R','V' (identity-skip)
__device__ inline void rot_pair(float Z[3][3], int ca, float cc, float ss) {
#pragma clang fp contract(off)
    if (cc == 1.0f && ss == 0.0f) return;
    if (ca == 0) {
#pragma unroll
        for (int i = 0; i < 3; ++i) { float t = Z[i][1]; Z[i][1] = cc * t - ss * Z[i][0]; Z[i][0] = ss * t + cc * Z[i][0]; }
    } else {
#pragma unroll
        for (int i = 0; i < 3; ++i) { float t = Z[i][2]; Z[i][2] = cc * t - ss * Z[i][1]; Z[i][1] = ss * t + cc * Z[i][1]; }
    }
}

__device__ inline void swap_cols(float Z[3][3], int a, int b) {
    if (a == 0 && b == 1) { for (int i = 0; i < 3; ++i) { float t = Z[i][0]; Z[i][0] = Z[i][1]; Z[i][1] = t; } }
    else if (a == 0 && b == 2) { for (int i = 0; i < 3; ++i) { float t = Z[i][0]; Z[i][0] = Z[i][2]; Z[i][2] = t; } }
    else { for (int i = 0; i < 3; ++i) { float t = Z[i][1]; Z[i][1] = Z[i][2]; Z[i][2] = t; } }
}

// faithful SSTEQR('I') for n=3 (1-based indices mirror the Fortran)
__device__ void steqr3(float d[3], float e[2], float Z[3][3]) {
#pragma clang fp contract(off)
    const float eps = 5.9604645e-08f;       // SLAMCH('E') = 2^-24
    const float eps2 = eps * eps;
    const float safmin = 1.17549435e-38f;   // 2^-126
    const float ssfmax = sqrtf(1.0f / safmin) / 3.0f;
    const float ssfmin = sqrtf(safmin) / eps2;
    const int n = 3;
    for (int r = 0; r < 3; ++r)
        for (int c = 0; c < 3; ++c) Z[r][c] = (r == c) ? 1.0f : 0.0f;
    const int nmaxit = n * 30;
    int jtot = 0;
    int l1 = 1;
    while (l1 <= n) {
        if (l1 > 1) e[l1 - 2] = 0.0f;
        int m = n;
        for (int mm_ = l1; mm_ <= n - 1; ++mm_) {
            float tst = fabsf(e[mm_ - 1]);
            if (tst == 0.0f) { m = mm_; break; }
            if (tst <= (sqrtf(fabsf(d[mm_ - 1])) * sqrtf(fabsf(d[mm_]))) * eps) {
                e[mm_ - 1] = 0.0f; m = mm_; break;
            }
        }
        int l = l1, lsv = l, lend = m, lendsv = lend;
        l1 = m + 1;
        if (lend == l) continue;
        float anorm = 0.0f;
        for (int i = l; i <= lend; ++i) anorm = fmaxf(anorm, fabsf(d[i - 1]));
        for (int i = l; i <= lend - 1; ++i) anorm = fmaxf(anorm, fabsf(e[i - 1]));
        int iscale = 0;
        if (anorm == 0.0f) continue;
        if (anorm > ssfmax) {
            iscale = 1; float sc = ssfmax / anorm;
            for (int i = l; i <= lend; ++i) d[i - 1] *= sc;
            for (int i = l; i <= lend - 1; ++i) e[i - 1] *= sc;
        } else if (anorm < ssfmin) {
            iscale = 2; float sc = ssfmin / anorm;
            for (int i = l; i <= lend; ++i) d[i - 1] *= sc;
            for (int i = l; i <= lend - 1; ++i) e[i - 1] *= sc;
        }
        if (fabsf(d[lend - 1]) < fabsf(d[l - 1])) { int t = l; l = lend; lend = t; }
        if (lend > l) {
            // ---- QL iteration ----
            for (;;) {
                int m2 = lend;
                if (l != lend) {
                    for (int i = l; i <= lend - 1; ++i) {
                        float tst = e[i - 1] * e[i - 1];
                        if (tst <= (eps2 * fabsf(d[i - 1])) * fabsf(d[i]) + safmin) { m2 = i; break; }
                    }
                }
                if (m2 < lend) e[m2 - 1] = 0.0f;
                float p = d[l - 1];
                if (m2 == l) { d[l - 1] = p; ++l; if (l <= lend) continue; break; }
                if (m2 == l + 1) {
                    float rt1, rt2, cc, ss;
                    slaev2_f(d[l - 1], e[l - 1], d[l], rt1, rt2, cc, ss);
                    rot_pair(Z, l - 1, cc, ss);
                    d[l - 1] = rt1; d[l] = rt2; e[l - 1] = 0.0f;
                    l += 2; if (l <= lend) continue; break;
                }
                if (jtot == nmaxit) break;
                ++jtot;
                float g = (d[l] - p) / (2.0f * e[l - 1]);
                float r = slapy2f(g, 1.0f);
                g = d[m2 - 1] - p + e[l - 1] / (g + copysignf(r, g));
                float s = 1.0f, c = 1.0f;
                p = 0.0f;
                float csv[2], ssv[2];
                for (int i = m2 - 1; i >= l; --i) {
                    float f = s * e[i - 1];
                    float b = c * e[i - 1];
                    slartg_f(g, f, c, s, r);
                    if (i != m2 - 1) e[i] = r;
                    g = d[i] - p;
                    r = (d[i - 1] - g) * s + 2.0f * c * b;
                    p = s * r;
                    d[i] = g + p;
                    g = c * r - b;
                    csv[i - l] = c; ssv[i - l] = -s;
                }
                int mmc = m2 - l + 1;
                for (int j = mmc - 1; j >= 1; --j) {
                    rot_pair(Z, (l - 1) + (j - 1), csv[j - 1], ssv[j - 1]);
                }
                d[l - 1] -= p;
                e[l - 1] = g;
            }
        } else {
            // ---- QR iteration ----
            for (;;) {
                int m2 = lend;
                if (l != lend) {
                    for (int i = l; i >= lend + 1; --i) {
                        float tst = e[i - 2] * e[i - 2];
                        if (tst <= (eps2 * fabsf(d[i - 1])) * fabsf(d[i - 2]) + safmin) { m2 = i; break; }
                    }
                }
                if (m2 > lend) e[m2 - 2] = 0.0f;
                float p = d[l - 1];
                if (m2 == l) { d[l - 1] = p; --l; if (l >= lend) continue; break; }
                if (m2 == l - 1) {
                    float rt1, rt2, cc, ss;
                    slaev2_f(d[l - 2], e[l - 2], d[l - 1], rt1, rt2, cc, ss);
                    rot_pair(Z, l - 2, cc, ss);
                    d[l - 2] = rt1; d[l - 1] = rt2; e[l - 2] = 0.0f;
                    l -= 2; if (l >= lend) continue; break;
                }
                if (jtot == nmaxit) break;
                ++jtot;
                float g = (d[l - 2] - p) / (2.0f * e[l - 2]);
                float r = slapy2f(g, 1.0f);
                g = d[m2 - 1] - p + e[l - 2] / (g + copysignf(r, g));
                float s = 1.0f, c = 1.0f;
                p = 0.0f;
                float csv[2], ssv[2];
                for (int i = m2; i <= l - 1; ++i) {
                    float f = s * e[i - 1];
                    float b = c * e[i - 1];
                    slartg_f(g, f, c, s, r);
                    if (i != m2) e[i - 2] = r;
                    g = d[i - 1] - p;
                    r = (d[i] - g) * s + 2.0f * c * b;
                    p = s * r;
                    d[i - 1] = g + p;
                    g = c * r - b;
                    csv[i - m2] = c; ssv[i - m2] = s;
                }
                int cnt = l - m2 + 1;
                for (int j = 1; j <= cnt - 1; ++j) {
                    rot_pair(Z, (m2 - 1) + (j - 1), csv[j - 1], ssv[j - 1]);
                }
                d[l - 1] -= p;
                e[l - 2] = g;
            }
        }
        if (iscale == 1) {
            float isc = anorm / ssfmax;
            for (int i = lsv; i <= lendsv; ++i) d[i - 1] *= isc;
            for (int i = lsv; i <= lendsv - 1; ++i) e[i - 1] *= isc;
        } else if (iscale == 2) {
            float isc = anorm / ssfmin;
            for (int i = lsv; i <= lendsv; ++i) d[i - 1] *= isc;
            for (int i = lsv; i <= lendsv - 1; ++i) e[i - 1] *= isc;
        }
        if (jtot >= nmaxit) break;
    }
    // selection-sort ascending with column swaps (SSTEQR label 160)
    for (int ii = 2; ii <= n; ++ii) {
        int i = ii - 1, kk = i;
        float p = d[i - 1];
        for (int j = ii; j <= n; ++j) if (d[j - 1] < p) { kk = j; p = d[j - 1]; }
        if (kk != i) { d[kk - 1] = d[i - 1]; d[i - 1] = p; swap_cols(Z, i - 1, kk - 1); }
    }
}

__global__ void eigen_kernel(const float* __restrict__ cov, float* __restrict__ out_n, int N) {
#pragma clang fp contract(off)
    int n = blockIdx.x * blockDim.x + threadIdx.x;
    if (n >= N) return;
    float a00 = cov[n * 6 + 0], a10 = cov[n * 6 + 1], a20 = cov[n * 6 + 2];
    float a11 = cov[n * 6 + 3], a21 = cov[n * 6 + 4], a22 = cov[n * 6 + 5];

    // SSYTD2 (lower), n=3. slarfg = Fortran (no FMA); ssymv/sdot/saxpy/ssyr2 =
    // OpenBLAS FMA kernels (every "+= a*b" fused).
    float tau = 0.0f, v2 = 0.0f, e0, d1, d2, e1;
    float xnorm = fabsf(a20);
    if (xnorm == 0.0f) { tau = 0.0f; v2 = 0.0f; e0 = a10; d1 = a11; d2 = a22; e1 = a21; }
    else {
        float beta = -copysignf(slapy2f(a10, xnorm), a10);
        tau = (beta - a10) / beta;
        float rinv = 1.0f / (a10 - beta);
        v2 = a20 * rinv;
        e0 = beta;
        float y1 = fmaf(tau, a21 * v2, tau * a11);
        float y2 = fmaf(tau * v2, a22, tau * a21);
        float dot = fmaf(y2, v2, y1);
        float al = -((0.5f * tau) * dot);
        float w1 = y1 + al;
        float w2 = fmaf(al, v2, y2);
        d1 = (a11 - w1) - w1;
        e1 = fmaf(v2, -w1, a21) - w2;
        d2 = fmaf(w2, -v2, fmaf(v2, -w2, a22));
    }
    float d[3] = { a00, d1, d2 };
    float e[2] = { e0, e1 };
    float Z[3][3];
    steqr3(d, e, Z);
    // SORMTR -> SORM2R -> SLARF: sgemv_t (FMA chain) + sger (FMA)
    if (tau != 0.0f) {
#pragma unroll
        for (int c2 = 0; c2 < 3; ++c2) {
            float sum = fmaf(Z[2][c2], v2, Z[1][c2]);
            float t = tau * sum;
            Z[1][c2] = Z[1][c2] - t;
            Z[2][c2] = fmaf(v2, -t, Z[2][c2]);
        }
    }
    // argsort(|lambda|) stable -> column of min |lambda|
    float A0 = fabsf(d[0]), A1 = fabsf(d[1]), A2 = fabsf(d[2]);
    int idx = 0; float best = A0;
    if (A1 < best) { idx = 1; best = A1; }
    if (A2 < best) { idx = 2; }
    float zx = (idx == 0) ? Z[0][0] : ((idx == 1) ? Z[0][1] : Z[0][2]);
    float zy = (idx == 0) ? Z[1][0] : ((idx == 1) ? Z[1][1] : Z[1][2]);
    float zz = (idx == 0) ? Z[2][0] : ((idx == 1) ? Z[2][1] : Z[2][2]);
    out_n[n * 3 + 0] = zx;
    out_n[n * 3 + 1] = zy;
    out_n[n * 3 + 2] = zz;
}

extern "C" void kernel_launch(void* const* d_in, const int* in_sizes, int n_in,
                              void* d_out, int out_size, void* d_ws, size_t ws_size,
                              hipStream_t stream) {
    const float* old_w = (const float*)d_in[0];
    const float* pos   = (const float*)d_in[1];
    const float* nrm   = (const float*)d_in[2];
    // d_in[3] edge_idx_l unused (redundant with dense_l)
    const int*   dense = (const int*)d_in[4];
    const float* sd    = (const float*)d_in[5];
    const float* W1    = (const float*)d_in[6];
    const float* b1    = (const float*)d_in[7];
    const float* W2    = (const float*)d_in[8];
    const float* b2    = (const float*)d_in[9];
    const float* W3    = (const float*)d_in[10];
    const float* b3    = (const float*)d_in[11];

    const int N = in_sizes[1] / 3;   // 50000
    float* ws = (float*)d_ws;
    float* cov = ws + COV_OFF;
    float* out_normals = (float*)d_out;           // N*3
    float* out_weights = (float*)d_out + N * 3;   // N*K

    prep_kernel<<<2, 256, 0, stream>>>(W1, b1, ws);
    gnn_kernel<<<(N + 7) / 8, 256, 0, stream>>>(old_w, pos, nrm, dense, sd, b2,
                                                W3, b3, W2, ws, out_weights, cov, N);
    eigen_kernel<<<(N + 255) / 256, 256, 0, stream>>>(cov, out_normals, N);
}